// Round 9
// baseline (51.340 us; speedup 1.0000x reference)
//
#include <hip/hip_runtime.h>
#include <cmath>

#define BN 8192
#define DIM 128
#define MARGIN_F 0.3f
#define NSPLIT 8            // column splits (1024 cols each)
#define CPS 1024
#define NT 8                // 128-col B tiles per panel
#define NPART (NSPLIT * 2)  // per-row partials: split x wc
#define FBLK 32
#define NLAB 128
#define IMAX 0x7FFFFFFF
#define IMIN 0x80000000

typedef __attribute__((ext_vector_type(4))) int i32x4;

__device__ __forceinline__ int imin3(int a, int b, int c) { return min(a, min(b, c)); }
__device__ __forceinline__ int imax3(int a, int b, int c) { return max(a, max(b, c)); }

// ---------------- K0: parallel counting-sort prep ----------------
// 1 block, fully parallel (r5's serial thread-0 scan was ~7us on one CU — the
// regression). Produces: binCur[128] = exclusive prefix (K1 rank cursors) and
// LR[128] = packed (lo|hi<<8) label range of each 64-row sorted group, via
// per-thread binary search over the inclusive histogram prefix.
__global__ __launch_bounds__(256) void sort_prep_k(
    const int* __restrict__ lab, int* __restrict__ binCur, int* __restrict__ LR)
{
  __shared__ int h[NLAB];
  __shared__ int incl[NLAB];
  const int t = threadIdx.x;
  if (t < NLAB) h[t] = 0;
  __syncthreads();
  for (int i = t; i < BN; i += 256) atomicAdd(&h[lab[i] & (NLAB - 1)], 1);
  __syncthreads();
  if (t < NLAB) incl[t] = h[t];
  __syncthreads();
  #pragma unroll
  for (int off = 1; off < NLAB; off <<= 1) {     // Hillis-Steele inclusive scan
    int v = (t < NLAB && t >= off) ? incl[t - off] : 0;
    __syncthreads();
    if (t < NLAB) incl[t] += v;
    __syncthreads();
  }
  if (t < NLAB) {
    binCur[t] = incl[t] - h[t];                  // exclusive prefix
    // label at sorted position p = smallest b with incl[b] > p (7-step bsearch)
    int p0 = t * 64, p1 = t * 64 + 63;
    int lo = 0, hi = NLAB - 1;
    while (lo < hi) { int m = (lo + hi) >> 1; if (incl[m] > p0) hi = m; else lo = m + 1; }
    int lab0 = lo;
    lo = lab0; hi = NLAB - 1;                    // p1 >= p0 -> start from lab0
    while (lo < hi) { int m = (lo + hi) >> 1; if (incl[m] > p1) hi = m; else lo = m + 1; }
    LR[t] = lab0 | (lo << 8);
  }
}

// ---------------- K1: norms + i8 quantize + label-sorted scatter ----------------
// Row w -> sorted slot dst = atomicAdd(binCur[lab[w]]) (order within a label is
// irrelevant: mining is min/max over sets). Emits sorted labS, sqvS, EnQ columns.
__global__ __launch_bounds__(256) void norm_cvt_k(
    const float* __restrict__ emb, const int* __restrict__ lab,
    float* __restrict__ sqvS, unsigned short* __restrict__ EnQ16,
    int* __restrict__ labS, int* __restrict__ binCur)
{
  int gt = blockIdx.x * blockDim.x + threadIdx.x;
  int w = gt >> 6;  // one wave per row
  int lane = threadIdx.x & 63;
  if (w >= BN) return;

  int lb = 0, dst = 0;
  if (lane == 0) { lb = lab[w] & (NLAB - 1); dst = atomicAdd(&binCur[lb], 1); }
  dst = __shfl(dst, 0);
  lb  = __shfl(lb, 0);

  float2 v = *reinterpret_cast<const float2*>(&emb[w * DIM + lane * 2]);
  float s = v.x * v.x + v.y * v.y;
  #pragma unroll
  for (int off = 32; off > 0; off >>= 1) s += __shfl_xor(s, off);
  float iv = 1.0f / fmaxf(sqrtf(s), 1e-12f);
  if (lane == 0) { sqvS[dst] = s * iv * iv; labS[dst] = lb; }
  int q0 = (int)rintf(127.0f * v.x * iv);
  int q1 = (int)rintf(127.0f * v.y * iv);
  unsigned short us = (unsigned short)((q0 & 255) | ((q1 & 255) << 8));
  int g = lane >> 3;                                  // k = 2*lane -> chunk g = lane/8
  EnQ16[(g * BN + dst) * 8 + (lane & 7)] = us;
}

// ---------------- K2: barrier-free i8-MFMA gram + sorted fast-path mining ----------------
// r6 PMC: VALUBusy 48% (~9.7us) is the spine, and mining (8 VALU per (mi,r) pair on
// all 67M dots) dominates it. With label-sorted rows/cols, a wave-uniform range test
// classifies each 64x64 tile: disjoint (~97%) -> every pair is a negative -> mining
// collapses to one v_max3 per (mi,r) (no label loads, no selects). Band tiles take
// the exact compare path. B-frags read directly from L2-resident EnQ (r8), no LDS,
// no barriers; half-deep pipeline mines previous half under current MFMA+loads.
__global__ __launch_bounds__(256, 2) void gram_mine_mfma_k(
    const char* __restrict__ EnQ, const int* __restrict__ labS,
    const int* __restrict__ LR,
    int* __restrict__ ap_part, int* __restrict__ an_part)
{
  const int tid = threadIdx.x;
  const int w = tid >> 6, l = tid & 63;
  const int wr = w >> 1, wc = w & 1;
  const int lrow = l & 15, lkg = l >> 4;

  const int rowBase = blockIdx.x * 128 + wr * 64;   // this wave's 64 rows
  const int panel   = blockIdx.y * CPS;

  const int LRr = LR[rowBase >> 6];
  const int rLo = LRr & 255, rHi = (LRr >> 8) & 255;

  // A fragments: 4 row-tiles x 2 K-steps (K=64 each), 16B per frag, coalesced
  i32x4 a[4][2];
  #pragma unroll
  for (int mi = 0; mi < 4; ++mi)
    #pragma unroll
    for (int kk = 0; kk < 2; ++kk)
      a[mi][kk] = *reinterpret_cast<const i32x4*>(
          EnQ + (((size_t)((kk << 2) + lkg) * BN + rowBase + mi * 16 + lrow) << 4));

  // row labels for the 16 rows this lane owns (sorted domain)
  int rlv[4][4];
  #pragma unroll
  for (int mi = 0; mi < 4; ++mi) {
    int rb = rowBase + mi * 16 + lkg * 4;
    #pragma unroll
    for (int r = 0; r < 4; ++r) rlv[mi][r] = labS[rb + r];
  }

  int ap[4][4], an[4][4];
  #pragma unroll
  for (int mi = 0; mi < 4; ++mi)
    #pragma unroll
    for (int r = 0; r < 4; ++r) { ap[mi][r] = IMAX; an[mi][r] = IMIN; }

  const i32x4 zf = {0, 0, 0, 0};   // shared zero C-operand

  // B pointers: two bases (kk=0,1), advanced 2048 B per 128-col tile
  const int colLane = wc * 64 + lrow;
  const char* bp0 = EnQ + (((size_t)lkg * BN + panel + colLane) << 4);
  const char* bp1 = bp0 + ((size_t)BN << 6);   // += 4*BN*16

  auto loadHalf = [&](i32x4 (&b)[2][2], const char* p0, const char* p1, int n0) {
    #pragma unroll
    for (int n = 0; n < 2; ++n) {
      b[0][n] = *reinterpret_cast<const i32x4*>(p0 + (n0 + n) * 256);
      b[1][n] = *reinterpret_cast<const i32x4*>(p1 + (n0 + n) * 256);
    }
  };
  auto mfmaHalf = [&](i32x4 (&A)[4][2], const i32x4 (&b)[2][2]) {
    #pragma unroll
    for (int mi = 0; mi < 4; ++mi)
      #pragma unroll
      for (int n = 0; n < 2; ++n)
        A[mi][n] = __builtin_amdgcn_mfma_i32_16x16x64_i8(a[mi][0], b[0][n], zf, 0, 0, 0);
    #pragma unroll
    for (int mi = 0; mi < 4; ++mi)
      #pragma unroll
      for (int n = 0; n < 2; ++n)
        A[mi][n] = __builtin_amdgcn_mfma_i32_16x16x64_i8(a[mi][1], b[1][n], A[mi][n], 0, 0, 0);
  };

  // FAST: disjoint label ranges -> all negatives, pure max
  auto mineFast = [&](const i32x4 (&A)[4][2]) {
    #pragma unroll
    for (int mi = 0; mi < 4; ++mi)
      #pragma unroll
      for (int r = 0; r < 4; ++r)
        an[mi][r] = imax3(an[mi][r], A[mi][0][r], A[mi][1][r]);
  };
  // MIXED: exact compare path (diag adds self-exclusion)
  auto mineMixed = [&](const i32x4 (&A)[4][2], int l0, int l1, int c0, int c1, bool dg) {
    if (!dg) {
      #pragma unroll
      for (int mi = 0; mi < 4; ++mi)
        #pragma unroll
        for (int r = 0; r < 4; ++r) {
          int d0 = A[mi][0][r], d1 = A[mi][1][r];
          bool s0 = (rlv[mi][r] == l0), s1 = (rlv[mi][r] == l1);
          int p0 = s0 ? d0 : IMAX;
          int p1 = s1 ? d1 : IMAX;
          int q0 = s0 ? IMIN : d0;
          int q1 = s1 ? IMIN : d1;
          ap[mi][r] = imin3(ap[mi][r], p0, p1);
          an[mi][r] = imax3(an[mi][r], q0, q1);
        }
    } else {
      #pragma unroll
      for (int mi = 0; mi < 4; ++mi)
        #pragma unroll
        for (int r = 0; r < 4; ++r) {
          int rloc = mi * 16 + lkg * 4 + r;
          int d0 = A[mi][0][r], d1 = A[mi][1][r];
          bool s0 = (rlv[mi][r] == l0), s1 = (rlv[mi][r] == l1);
          bool e0 = (rloc == c0), e1 = (rloc == c1);
          int p0 = (s0 && !e0) ? d0 : IMAX;
          int p1 = (s1 && !e1) ? d1 : IMAX;
          int q0 = s0 ? IMIN : d0;
          int q1 = s1 ? IMIN : d1;
          ap[mi][r] = imin3(ap[mi][r], p0, p1);
          an[mi][r] = imax3(an[mi][r], q0, q1);
        }
    }
  };

  i32x4 accA[4][2], accB[4][2];
  i32x4 bA[2][2], bB[2][2];
  int lp0 = 0, lp1 = 0;
  bool diagP = false, mixedP = false;

  loadHalf(bA, bp0, bp1, 0);   // tile 0, half 0

  #pragma unroll 1
  for (int ct = 0; ct < NT; ++ct) {
    const int colBase = panel + ct * 128 + wc * 64;
    const int LRc = LR[colBase >> 6];
    const int cLo = LRc & 255, cHi = (LRc >> 8) & 255;
    const bool mixed = (cHi >= rLo) && (cLo <= rHi);
    const bool diag  = (rowBase == colBase);          // diag => mixed

    int l0 = 0, l1 = 0, l2 = 0, l3 = 0;
    if (mixed) {
      l0 = labS[colBase + lrow];       l1 = labS[colBase + 16 + lrow];
      l2 = labS[colBase + 32 + lrow];  l3 = labS[colBase + 48 + lrow];
    }

    loadHalf(bB, bp0, bp1, 2);           // this tile, half 1 (in flight)
    mfmaHalf(accA, bA);                  // half 0 MFMA (waits on bA)
    if (ct > 0) {                        // previous tile's half 1
      if (mixedP) mineMixed(accB, lp0, lp1, 32 + lrow, 48 + lrow, diagP);
      else        mineFast(accB);
    }

    bp0 += 2048; bp1 += 2048;
    if (ct + 1 < NT) loadHalf(bA, bp0, bp1, 0);   // next tile, half 0 (in flight)

    mfmaHalf(accB, bB);                  // half 1 MFMA
    if (mixed) mineMixed(accA, l0, l1, 0 + lrow, 16 + lrow, diag);
    else       mineFast(accA);

    lp0 = l2; lp1 = l3; diagP = diag; mixedP = mixed;
  }
  // drain: last tile's half 1
  if (mixedP) mineMixed(accB, lp0, lp1, 32 + lrow, 48 + lrow, diagP);
  else        mineFast(accB);

  // butterfly-reduce across the 16 lrow lanes sharing each C row, write partials
  const int part = blockIdx.y * 2 + wc;
  #pragma unroll
  for (int mi = 0; mi < 4; ++mi)
    #pragma unroll
    for (int r = 0; r < 4; ++r) {
      int p = ap[mi][r], n = an[mi][r];
      #pragma unroll
      for (int off = 1; off < 16; off <<= 1) {
        p = min(p, __shfl_xor(p, off));
        n = max(n, __shfl_xor(n, off));
      }
      if (lrow == 0) {
        int rg = rowBase + mi * 16 + lkg * 4 + r;
        ap_part[part * BN + rg] = p;
        an_part[part * BN + rg] = n;
      }
    }
}

// ---------------- K3a: per-row combine (sorted domain; mean is perm-invariant) ----------------
__global__ __launch_bounds__(256) void finalize_a_k(
    const int* __restrict__ ap_part, const int* __restrict__ an_part,
    const float* __restrict__ sqvS,
    float* __restrict__ blk_sum, float* __restrict__ blk_cnt)
{
  int r = blockIdx.x * 256 + threadIdx.x;   // FBLK*256 == BN
  int apt = IMAX, ant = IMIN;               // min-idot pos / max-idot neg
  #pragma unroll 8
  for (int s = 0; s < NPART; ++s) {
    apt = min(apt, ap_part[s * BN + r]);
    ant = max(ant, an_part[s * BN + r]);
  }
  float sum = 0.f, cnt = 0.f;
  if (apt != IMAX && ant != IMIN) {
    const float sc = 2.0f / (127.0f * 127.0f);
    float rs1 = sqvS[r] + 1.0f;
    float dap = sqrtf(fmaxf(fmaf(-sc, (float)apt, rs1), 0.f));
    float dan = sqrtf(fmaxf(fmaf(-sc, (float)ant, rs1), 0.f));
    sum = fmaxf(dap - dan + MARGIN_F, 0.f);
    cnt = 1.f;
  }
  #pragma unroll
  for (int off = 32; off > 0; off >>= 1) {
    sum += __shfl_xor(sum, off);
    cnt += __shfl_xor(cnt, off);
  }
  __shared__ float ssum[4], scnt[4];
  int wv = threadIdx.x >> 6;
  if ((threadIdx.x & 63) == 0) { ssum[wv] = sum; scnt[wv] = cnt; }
  __syncthreads();
  if (threadIdx.x == 0) {
    blk_sum[blockIdx.x] = ssum[0] + ssum[1] + ssum[2] + ssum[3];
    blk_cnt[blockIdx.x] = scnt[0] + scnt[1] + scnt[2] + scnt[3];
  }
}

// ---------------- K3b: final scalar ----------------
__global__ __launch_bounds__(64) void finalize_b_k(
    const float* __restrict__ blk_sum, const float* __restrict__ blk_cnt,
    float* __restrict__ out)
{
  int l = threadIdx.x;
  float s = (l < FBLK) ? blk_sum[l] : 0.f;
  float c = (l < FBLK) ? blk_cnt[l] : 0.f;
  #pragma unroll
  for (int off = 32; off > 0; off >>= 1) {
    s += __shfl_xor(s, off);
    c += __shfl_xor(c, off);
  }
  if (l == 0) out[0] = (c > 0.f) ? (s / c) : 0.f;
}

extern "C" void kernel_launch(void* const* d_in, const int* in_sizes, int n_in,
                              void* d_out, int out_size, void* d_ws, size_t ws_size,
                              hipStream_t stream)
{
  const float* emb = (const float*)d_in[0];
  const int*   lab = (const int*)d_in[1];
  float* out = (float*)d_out;
  float* ws  = (float*)d_ws;

  float* sqvS     = ws;                             // BN floats
  int*   ap_part  = (int*)(sqvS + BN);              // NPART*BN ints
  int*   an_part  = ap_part + NPART * BN;           // NPART*BN ints
  float* blk_sum  = (float*)(an_part + NPART * BN); // FBLK
  float* blk_cnt  = blk_sum + FBLK;                 // FBLK
  int*   labS     = (int*)(blk_cnt + FBLK);         // BN
  int*   binCur   = labS + BN;                      // NLAB
  int*   LR       = binCur + NLAB;                  // NLAB
  char*  EnQ      = (char*)(LR + NLAB + 16);        // BN*DIM i8, k-major (~1 MB)

  sort_prep_k<<<dim3(1), 256, 0, stream>>>(lab, binCur, LR);
  norm_cvt_k<<<dim3(BN / 4), 256, 0, stream>>>(emb, lab, sqvS, (unsigned short*)EnQ,
                                               labS, binCur);
  gram_mine_mfma_k<<<dim3(BN / 128, NSPLIT), 256, 0, stream>>>(EnQ, labS, LR,
                                                               ap_part, an_part);
  finalize_a_k<<<dim3(FBLK), 256, 0, stream>>>(ap_part, an_part, sqvS, blk_sum, blk_cnt);
  finalize_b_k<<<dim3(1), 64, 0, stream>>>(blk_sum, blk_cnt, out);
}

// Round 10
// 40.401 us; speedup vs baseline: 1.2708x; 1.2708x over previous
//
#include <hip/hip_runtime.h>
#include <cmath>

#define BN 8192
#define DIM 128
#define MARGIN_F 0.3f
#define NSPLIT 16           // column splits (512 cols each) -> 1024 blocks, >=3 blocks/CU
#define CPS 512
#define NT 4                // 128-col B tiles per panel
#define NPART (NSPLIT * 2)  // per-row partials: split x wc
#define FBLK 32
#define IMAX 0x7FFFFFFF
#define IMIN 0x80000000

typedef __attribute__((ext_vector_type(4))) int i32x4;

__device__ __forceinline__ int imin3(int a, int b, int c) { return min(a, min(b, c)); }
__device__ __forceinline__ int imax3(int a, int b, int c) { return max(a, max(b, c)); }

// ---------------- K1: fp32 row norms -> sqv + k-major i8 quantized copy ----------------
// Also builds LP: packed column-label table. LP[cb*16 + lrow] holds the 4 label bytes
// {lab[cb*64 + n*16 + lrow], n=0..3} so K2 reads ONE u32 per tile instead of 4
// scattered global loads (cb = 64-col group index, 128 groups -> 8 KB, L2-resident).
__global__ __launch_bounds__(256) void norm_cvt_k(
    const float* __restrict__ emb, const int* __restrict__ lab,
    float* __restrict__ sqv, unsigned short* __restrict__ EnQ16,
    unsigned* __restrict__ LP)
{
  int gt = blockIdx.x * blockDim.x + threadIdx.x;
  if (gt < 2048) {
    int base = (gt >> 4) * 64 + (gt & 15);
    LP[gt] = (unsigned)(lab[base] & 255) | ((unsigned)(lab[base + 16] & 255) << 8) |
             ((unsigned)(lab[base + 32] & 255) << 16) | ((unsigned)(lab[base + 48] & 255) << 24);
  }

  int w = gt >> 6;  // one wave per row
  int lane = threadIdx.x & 63;
  if (w >= BN) return;
  float2 v = *reinterpret_cast<const float2*>(&emb[w * DIM + lane * 2]);
  float s = v.x * v.x + v.y * v.y;
  #pragma unroll
  for (int off = 32; off > 0; off >>= 1) s += __shfl_xor(s, off);
  float iv = 1.0f / fmaxf(sqrtf(s), 1e-12f);
  if (lane == 0) sqv[w] = s * iv * iv;
  int q0 = (int)rintf(127.0f * v.x * iv);
  int q1 = (int)rintf(127.0f * v.y * iv);
  unsigned short us = (unsigned short)((q0 & 255) | ((q1 & 255) << 8));
  int g = lane >> 3;                                  // k = 2*lane -> chunk g = lane/8
  EnQ16[(g * BN + w) * 8 + (lane & 7)] = us;
}

// ---------------- K2: barrier-free i8-MFMA gram + mining, 3-waves/SIMD regime ----------------
// All K2 variants stuck at ~20us were 2 waves/SIMD (~190 VGPR double-acc). r6 PMC:
// VALU 48% busy / ~50% idle / Occ 17.6% -> per-wave dependency latency with no TLP
// cover. This version: single acc (TLP replaces the r7 in-wave pipeline), alternating
// b0/b1 prefetch, launch_bounds(256,3) caps regs at 170 -> 3 waves/SIMD; NSPLIT=16
// supplies >=3 blocks/CU. Direct L2 reads of EnQ (1 MB resident), no LDS, no barriers.
__global__ __launch_bounds__(256, 3) void gram_mine_mfma_k(
    const char* __restrict__ EnQ, const int* __restrict__ lab,
    const unsigned* __restrict__ LP,
    int* __restrict__ ap_part, int* __restrict__ an_part)
{
  const int tid = threadIdx.x;
  const int w = tid >> 6, l = tid & 63;
  const int wr = w >> 1, wc = w & 1;
  const int lrow = l & 15, lkg = l >> 4;

  const int rowBase = blockIdx.x * 128 + wr * 64;   // this wave's 64 rows
  const int panel   = blockIdx.y * CPS;

  // A fragments: 4 row-tiles x 2 K-steps (K=64 each), 16B per frag, coalesced
  i32x4 a[4][2];
  #pragma unroll
  for (int mi = 0; mi < 4; ++mi)
    #pragma unroll
    for (int kk = 0; kk < 2; ++kk)
      a[mi][kk] = *reinterpret_cast<const i32x4*>(
          EnQ + (((size_t)((kk << 2) + lkg) * BN + rowBase + mi * 16 + lrow) << 4));

  // row labels for the 16 rows this lane owns (tile-invariant)
  int rlv[4][4];
  #pragma unroll
  for (int mi = 0; mi < 4; ++mi) {
    int rb = rowBase + mi * 16 + lkg * 4;
    #pragma unroll
    for (int r = 0; r < 4; ++r) rlv[mi][r] = lab[rb + r] & 255;
  }

  int ap[4][4], an[4][4];
  #pragma unroll
  for (int mi = 0; mi < 4; ++mi)
    #pragma unroll
    for (int r = 0; r < 4; ++r) { ap[mi][r] = IMAX; an[mi][r] = IMIN; }

  const i32x4 zf = {0, 0, 0, 0};   // shared zero C-operand

  // B pointers: two bases (kk=0,1), advanced 2048 B per 128-col tile
  const int colLane = wc * 64 + lrow;
  const char* bp0 = EnQ + (((size_t)lkg * BN + panel + colLane) << 4);
  const char* bp1 = bp0 + ((size_t)BN << 6);   // += 4*BN*16

  auto loadHalf = [&](i32x4 (&b)[2][2], const char* p0, const char* p1, int n0) {
    #pragma unroll
    for (int n = 0; n < 2; ++n) {
      b[0][n] = *reinterpret_cast<const i32x4*>(p0 + (n0 + n) * 256);
      b[1][n] = *reinterpret_cast<const i32x4*>(p1 + (n0 + n) * 256);
    }
  };
  auto mfmaHalf = [&](i32x4 (&A)[4][2], const i32x4 (&b)[2][2]) {
    #pragma unroll
    for (int mi = 0; mi < 4; ++mi)
      #pragma unroll
      for (int n = 0; n < 2; ++n)
        A[mi][n] = __builtin_amdgcn_mfma_i32_16x16x64_i8(a[mi][0], b[0][n], zf, 0, 0, 0);
    #pragma unroll
    for (int mi = 0; mi < 4; ++mi)
      #pragma unroll
      for (int n = 0; n < 2; ++n)
        A[mi][n] = __builtin_amdgcn_mfma_i32_16x16x64_i8(a[mi][1], b[1][n], A[mi][n], 0, 0, 0);
  };

  // mine one 64x32 half: l0/l1 = column labels of the two 16-col subtiles (per-lane),
  // c0/c1 = local column index of this lane in those subtiles (self-exclusion on diag)
  auto mineTile = [&](const i32x4 (&A)[4][2], int l0, int l1, int c0, int c1, bool dg) {
    if (!dg) {
      #pragma unroll
      for (int mi = 0; mi < 4; ++mi)
        #pragma unroll
        for (int r = 0; r < 4; ++r) {
          int d0 = A[mi][0][r], d1 = A[mi][1][r];
          bool s0 = (rlv[mi][r] == l0), s1 = (rlv[mi][r] == l1);
          int p0 = s0 ? d0 : IMAX;
          int p1 = s1 ? d1 : IMAX;
          int q0 = s0 ? IMIN : d0;
          int q1 = s1 ? IMIN : d1;
          ap[mi][r] = imin3(ap[mi][r], p0, p1);
          an[mi][r] = imax3(an[mi][r], q0, q1);
        }
    } else {
      #pragma unroll
      for (int mi = 0; mi < 4; ++mi)
        #pragma unroll
        for (int r = 0; r < 4; ++r) {
          int rloc = mi * 16 + lkg * 4 + r;
          int d0 = A[mi][0][r], d1 = A[mi][1][r];
          bool s0 = (rlv[mi][r] == l0), s1 = (rlv[mi][r] == l1);
          bool e0 = (rloc == c0), e1 = (rloc == c1);
          int p0 = (s0 && !e0) ? d0 : IMAX;
          int p1 = (s1 && !e1) ? d1 : IMAX;
          int q0 = s0 ? IMIN : d0;
          int q1 = s1 ? IMIN : d1;
          ap[mi][r] = imin3(ap[mi][r], p0, p1);
          an[mi][r] = imax3(an[mi][r], q0, q1);
        }
    }
  };

  i32x4 acc[4][2];
  i32x4 b0[2][2], b1[2][2];

  loadHalf(b0, bp0, bp1, 0);   // tile 0, half 0

  #pragma unroll 1
  for (int ct = 0; ct < NT; ++ct) {
    const int colBase = panel + ct * 128 + wc * 64;
    const bool diag = (rowBase == colBase);

    // packed column labels for this wave's 64 cols: one u32
    const unsigned LPv = LP[(colBase >> 6) * 16 + lrow];
    const int l0 = (int)(LPv & 255u),         l1 = (int)((LPv >> 8) & 255u);
    const int l2 = (int)((LPv >> 16) & 255u), l3 = (int)(LPv >> 24);

    loadHalf(b1, bp0, bp1, 2);                    // this tile, half 1 (in flight)
    mfmaHalf(acc, b0);                            // half 0 MFMA (waits on b0)
    mineTile(acc, l0, l1, 0 + lrow, 16 + lrow, diag);

    bp0 += 2048; bp1 += 2048;
    if (ct + 1 < NT) loadHalf(b0, bp0, bp1, 0);   // next tile, half 0 (in flight)
    mfmaHalf(acc, b1);                            // half 1 MFMA
    mineTile(acc, l2, l3, 32 + lrow, 48 + lrow, diag);
  }

  // butterfly-reduce across the 16 lrow lanes sharing each C row, write partials
  const int part = blockIdx.y * 2 + wc;
  #pragma unroll
  for (int mi = 0; mi < 4; ++mi)
    #pragma unroll
    for (int r = 0; r < 4; ++r) {
      int p = ap[mi][r], n = an[mi][r];
      #pragma unroll
      for (int off = 1; off < 16; off <<= 1) {
        p = min(p, __shfl_xor(p, off));
        n = max(n, __shfl_xor(n, off));
      }
      if (lrow == 0) {
        int rg = rowBase + mi * 16 + lkg * 4 + r;
        ap_part[part * BN + rg] = p;
        an_part[part * BN + rg] = n;
      }
    }
}

// ---------------- K3a: per-row combine, d = sqrt(rs + 1 - 2*dot/127^2), margin ----------------
__global__ __launch_bounds__(256) void finalize_a_k(
    const int* __restrict__ ap_part, const int* __restrict__ an_part,
    const float* __restrict__ sqv,
    float* __restrict__ blk_sum, float* __restrict__ blk_cnt)
{
  int r = blockIdx.x * 256 + threadIdx.x;   // FBLK*256 == BN
  int apt = IMAX, ant = IMIN;               // min-idot pos / max-idot neg
  #pragma unroll 8
  for (int s = 0; s < NPART; ++s) {
    apt = min(apt, ap_part[s * BN + r]);
    ant = max(ant, an_part[s * BN + r]);
  }
  float sum = 0.f, cnt = 0.f;
  if (apt != IMAX && ant != IMIN) {
    const float sc = 2.0f / (127.0f * 127.0f);
    float rs1 = sqv[r] + 1.0f;
    float dap = sqrtf(fmaxf(fmaf(-sc, (float)apt, rs1), 0.f));
    float dan = sqrtf(fmaxf(fmaf(-sc, (float)ant, rs1), 0.f));
    sum = fmaxf(dap - dan + MARGIN_F, 0.f);
    cnt = 1.f;
  }
  #pragma unroll
  for (int off = 32; off > 0; off >>= 1) {
    sum += __shfl_xor(sum, off);
    cnt += __shfl_xor(cnt, off);
  }
  __shared__ float ssum[4], scnt[4];
  int wv = threadIdx.x >> 6;
  if ((threadIdx.x & 63) == 0) { ssum[wv] = sum; scnt[wv] = cnt; }
  __syncthreads();
  if (threadIdx.x == 0) {
    blk_sum[blockIdx.x] = ssum[0] + ssum[1] + ssum[2] + ssum[3];
    blk_cnt[blockIdx.x] = scnt[0] + scnt[1] + scnt[2] + scnt[3];
  }
}

// ---------------- K3b: final scalar ----------------
__global__ __launch_bounds__(64) void finalize_b_k(
    const float* __restrict__ blk_sum, const float* __restrict__ blk_cnt,
    float* __restrict__ out)
{
  int l = threadIdx.x;
  float s = (l < FBLK) ? blk_sum[l] : 0.f;
  float c = (l < FBLK) ? blk_cnt[l] : 0.f;
  #pragma unroll
  for (int off = 32; off > 0; off >>= 1) {
    s += __shfl_xor(s, off);
    c += __shfl_xor(c, off);
  }
  if (l == 0) out[0] = (c > 0.f) ? (s / c) : 0.f;
}

extern "C" void kernel_launch(void* const* d_in, const int* in_sizes, int n_in,
                              void* d_out, int out_size, void* d_ws, size_t ws_size,
                              hipStream_t stream)
{
  const float* emb = (const float*)d_in[0];
  const int*   lab = (const int*)d_in[1];
  float* out = (float*)d_out;
  float* ws  = (float*)d_ws;

  float*    sqv     = ws;                          // BN floats
  int*      ap_part = (int*)(sqv + BN);            // NPART*BN ints
  int*      an_part = ap_part + NPART * BN;        // NPART*BN ints
  float*    blk_sum = (float*)(an_part + NPART * BN);  // FBLK
  float*    blk_cnt = blk_sum + FBLK;              // FBLK
  unsigned* LP      = (unsigned*)(blk_cnt + FBLK); // 2048 u32 (8 KB)
  char*     EnQ     = (char*)(LP + 2048);          // BN*DIM i8, k-major (~1 MB)

  norm_cvt_k<<<dim3(BN / 4), 256, 0, stream>>>(emb, lab, sqv, (unsigned short*)EnQ, LP);
  gram_mine_mfma_k<<<dim3(BN / 128, NSPLIT), 256, 0, stream>>>(EnQ, lab, LP, ap_part, an_part);
  finalize_a_k<<<dim3(FBLK), 256, 0, stream>>>(ap_part, an_part, sqv, blk_sum, blk_cnt);
  finalize_b_k<<<dim3(1), 64, 0, stream>>>(blk_sum, blk_cnt, out);
}